// Round 1
// baseline (681.315 us; speedup 1.0000x reference)
//
#include <hip/hip_runtime.h>
#include <hip/hip_bf16.h>

// Problem constants
#define B_  8
#define C_  64
#define H_  128
#define W_  128
#define HW  16384           // H_*W_
#define CHW 1048576         // C_*HW
#define EPSV 1e-5f

typedef __attribute__((ext_vector_type(8))) unsigned short ushort8;
typedef __attribute__((ext_vector_type(4))) unsigned short ushort4_t;

// bf16 <-> f32 helpers (bit-level, RNE), avoids API version issues
static __device__ __forceinline__ float b2f(unsigned short u) {
    union { unsigned int i; float f; } x; x.i = ((unsigned int)u) << 16; return x.f;
}
static __device__ __forceinline__ unsigned short f2b(float f) {
    union { float f; unsigned int i; } x; x.f = f;
    unsigned int i = x.i;
    unsigned int lsb = (i >> 16) & 1u;
    i += 0x7fffu + lsb;   // round-to-nearest-even
    return (unsigned short)(i >> 16);
}

// ---------------------------------------------------------------------------
// Kernel 0: weight prep — transpose to [c][..][o] layouts, fold BN into conv
// weights: WT1[c][dy][dx][o] = conv1_w[o][c][dy][dx] * inv1[o];
// beta = bias - mean*inv.
// ---------------------------------------------------------------------------
__global__ void prep_kernel(const float* __restrict__ Wq, const float* __restrict__ Wk,
                            const float* __restrict__ Wv,
                            const float* __restrict__ c1w,
                            const float* __restrict__ bn1s, const float* __restrict__ bn1b,
                            const float* __restrict__ bn1m, const float* __restrict__ bn1v,
                            const float* __restrict__ c2w,
                            const float* __restrict__ bn2s, const float* __restrict__ bn2b,
                            const float* __restrict__ bn2m, const float* __restrict__ bn2v,
                            float* __restrict__ wqT, float* __restrict__ wkT,
                            float* __restrict__ wvT, float* __restrict__ wt1,
                            float* __restrict__ w2T, float* __restrict__ beta1,
                            float* __restrict__ beta2)
{
    int i = blockIdx.x * blockDim.x + threadIdx.x;
    if (i < 12288) {                       // Wq/Wk/Wv transpose: [o][c] -> [c][o]
        int p = i >> 12, r = i & 4095, c = r >> 6, o = r & 63;
        const float* src = (p == 0) ? Wq : ((p == 1) ? Wk : Wv);
        float* dst = (p == 0) ? wqT : ((p == 1) ? wkT : wvT);
        dst[c * 64 + o] = src[o * 64 + c];
    } else if (i < 49152) {                // conv1 3x3: [o][c][dy][dx] -> [c*9+dy*3+dx][o], fold inv1
        int j = i - 12288; int o = j & 63; int rest = j >> 6;  // rest = c*9+dy*3+dx
        float inv = bn1s[o] * rsqrtf(bn1v[o] + EPSV);
        wt1[j] = c1w[o * 576 + rest] * inv;
    } else if (i < 53248) {                // conv2 1x1: [o][c] -> [c][o], fold inv2
        int j = i - 49152; int c = j >> 6, o = j & 63;
        float inv = bn2s[o] * rsqrtf(bn2v[o] + EPSV);
        w2T[c * 64 + o] = c2w[o * 64 + c] * inv;
    } else if (i < 53376) {
        int j = i - 53248;
        if (j < 64) {
            float inv = bn1s[j] * rsqrtf(bn1v[j] + EPSV);
            beta1[j] = bn1b[j] - bn1m[j] * inv;
        } else {
            int o = j - 64;
            float inv = bn2s[o] * rsqrtf(bn2v[o] + EPSV);
            beta2[o] = bn2b[o] - bn2m[o] * inv;
        }
    }
}

// ---------------------------------------------------------------------------
// Kernel 1: fused Q/K/V 1x1 projections. Block = (batch, 128-position tile),
// 128 threads, each thread owns one position with 64 f32 accumulators.
// Weights read wave-uniform (scalar path) from transposed [c][o] layout.
// ---------------------------------------------------------------------------
__global__ __launch_bounds__(128) void qkv_kernel(
    const float* __restrict__ x1, const float* __restrict__ xc,
    const float* __restrict__ wqT, const float* __restrict__ wkT,
    const float* __restrict__ wvT,
    const float* __restrict__ bq, const float* __restrict__ bk,
    const float* __restrict__ bv,
    unsigned short* __restrict__ q, unsigned short* __restrict__ k,
    unsigned short* __restrict__ v)
{
    __shared__ float xs[64][128];   // 32 KB
    int b = blockIdx.x >> 7;
    int posBase = (blockIdx.x & 127) << 7;
    int t = threadIdx.x;
    int base = b * CHW + posBase;

    // ---- x_1 tile -> Q
    for (int c = 0; c < 64; ++c) xs[c][t] = x1[base + c * HW + t];
    __syncthreads();
    {
        float acc[64];
        #pragma unroll
        for (int o = 0; o < 64; ++o) acc[o] = 0.f;
        for (int c = 0; c < 64; ++c) {
            float xv = xs[c][t];
            const float* wr = wqT + c * 64;     // wave-uniform
            #pragma unroll
            for (int o = 0; o < 64; ++o) acc[o] = fmaf(wr[o], xv, acc[o]);
        }
        for (int o = 0; o < 64; ++o)
            q[base + o * HW + t] = f2b(acc[o] + bq[o]);
    }
    __syncthreads();
    // ---- x_cur tile -> K, V
    for (int c = 0; c < 64; ++c) xs[c][t] = xc[base + c * HW + t];
    __syncthreads();
    {
        float acc[64];
        #pragma unroll
        for (int o = 0; o < 64; ++o) acc[o] = 0.f;
        for (int c = 0; c < 64; ++c) {
            float xv = xs[c][t];
            const float* wr = wkT + c * 64;
            #pragma unroll
            for (int o = 0; o < 64; ++o) acc[o] = fmaf(wr[o], xv, acc[o]);
        }
        for (int o = 0; o < 64; ++o)
            k[base + o * HW + t] = f2b(acc[o] + bk[o]);
    }
    {
        float acc[64];
        #pragma unroll
        for (int o = 0; o < 64; ++o) acc[o] = 0.f;
        for (int c = 0; c < 64; ++c) {
            float xv = xs[c][t];
            const float* wr = wvT + c * 64;
            #pragma unroll
            for (int o = 0; o < 64; ++o) acc[o] = fmaf(wr[o], xv, acc[o]);
        }
        for (int o = 0; o < 64; ++o)
            v[base + o * HW + t] = f2b(acc[o] + bv[o]);
    }
}

// ---------------------------------------------------------------------------
// Kernel 2: attention per (b,c). eT[v][w] = sum_h K[h][v]*Q[h][w]  (transposed
// energy so softmax over w is a contiguous row op). A stored transposed
// As[w][v]; V staged transposed vsT[w][h] (pad 136: conflict-free writes,
// 16B-aligned reads). out[h][v] = sum_w vsT[w][h]*As[w][v]; y = g*out + x_cur.
// LDS arena 131584 B (dynamic).
// ---------------------------------------------------------------------------
__global__ __launch_bounds__(256) void attn_kernel(
    const unsigned short* __restrict__ q, const unsigned short* __restrict__ k,
    const unsigned short* __restrict__ v, const float* __restrict__ xc,
    const float* __restrict__ gamma_p, unsigned short* __restrict__ y)
{
    extern __shared__ __align__(16) char arena[];
    unsigned short* qf = (unsigned short*)arena;                       // [128][128] bf16
    unsigned short* kf = (unsigned short*)(arena + 32768);             // [128][128] bf16
    float (*eT)[129] = (float(*)[129])(arena + 65536);                 // [128][129] f32
    unsigned short (*As)[128] = (unsigned short(*)[128])(arena);       // over qf (dead)
    float* pm = (float*)(arena + 32768);                               // over kf (dead)
    float* ps = (float*)(arena + 33792);
    unsigned short (*vsT)[136] = (unsigned short(*)[136])(arena + 65536); // over eT (dead)

    int bc = blockIdx.x;
    int base = bc * HW;
    int t = threadIdx.x;
    float g = gamma_p[0];

    // stage Q,K (bf16)
    for (int idx = t; idx < HW; idx += 256) {
        qf[idx] = q[base + idx];
        kf[idx] = k[base + idx];
    }
    __syncthreads();

    // ---- phase 1: eT[v][w] = sum_h K[h][v] * Q[h][w], 8x8 register tiles
    {
        int vt = (t >> 4) << 3;
        int wt = (t & 15) << 3;
        float acc[8][8];
        #pragma unroll
        for (int i = 0; i < 8; ++i)
            #pragma unroll
            for (int j = 0; j < 8; ++j) acc[i][j] = 0.f;
        for (int h = 0; h < 128; ++h) {
            ushort8 kv8 = *(const ushort8*)(kf + h * 128 + vt);
            ushort8 qv8 = *(const ushort8*)(qf + h * 128 + wt);
            float kv[8], qv[8];
            #pragma unroll
            for (int j = 0; j < 8; ++j) { kv[j] = b2f(kv8[j]); qv[j] = b2f(qv8[j]); }
            #pragma unroll
            for (int i = 0; i < 8; ++i)
                #pragma unroll
                for (int j = 0; j < 8; ++j)
                    acc[i][j] = fmaf(kv[i], qv[j], acc[i][j]);
        }
        #pragma unroll
        for (int i = 0; i < 8; ++i)
            #pragma unroll
            for (int j = 0; j < 8; ++j)
                eT[vt + i][wt + j] = acc[i][j];
    }
    __syncthreads();

    // ---- phase 2: row softmax over w; write As[w][v] = bf16(p)
    {
        int vv = t & 127, hf = t >> 7;
        int w0 = hf << 6;
        float m = -1e30f;
        for (int w = 0; w < 64; ++w) m = fmaxf(m, eT[vv][w0 + w]);
        pm[hf * 128 + vv] = m;
        __syncthreads();
        m = fmaxf(pm[vv], pm[128 + vv]);
        float s = 0.f;
        for (int w = 0; w < 64; ++w) {
            float e = __expf(eT[vv][w0 + w] - m);
            eT[vv][w0 + w] = e;
            s += e;
        }
        ps[hf * 128 + vv] = s;
        __syncthreads();
        float rinv = 1.f / (ps[vv] + ps[128 + vv]);
        for (int w = 0; w < 64; ++w)
            As[w0 + w][vv] = f2b(eT[vv][w0 + w] * rinv);
    }
    __syncthreads();   // eT fully consumed; As complete

    // stage V transposed: vsT[w][h] = V[h][w]
    for (int idx = t; idx < HW; idx += 256) {
        int hh = idx >> 7, ww = idx & 127;
        vsT[ww][hh] = v[base + idx];
    }
    __syncthreads();

    // ---- phase 3: out[h][v] = sum_w vsT[w][h] * As[w][v]; y = g*out + x_cur
    {
        int ht = (t >> 4) << 3;
        int vt = (t & 15) << 3;
        float acc[8][8];
        #pragma unroll
        for (int i = 0; i < 8; ++i)
            #pragma unroll
            for (int j = 0; j < 8; ++j) acc[i][j] = 0.f;
        for (int w = 0; w < 128; ++w) {
            ushort8 v8 = *(const ushort8*)&vsT[w][ht];
            ushort8 a8 = *(const ushort8*)&As[w][vt];
            float vv[8], av[8];
            #pragma unroll
            for (int j = 0; j < 8; ++j) { vv[j] = b2f(v8[j]); av[j] = b2f(a8[j]); }
            #pragma unroll
            for (int i = 0; i < 8; ++i)
                #pragma unroll
                for (int j = 0; j < 8; ++j)
                    acc[i][j] = fmaf(vv[i], av[j], acc[i][j]);
        }
        const float* xb = xc + base;
        #pragma unroll
        for (int i = 0; i < 8; ++i)
            #pragma unroll
            for (int j = 0; j < 8; ++j) {
                int idx = (ht + i) * 128 + vt + j;
                y[base + idx] = f2b(fmaf(g, acc[i][j], xb[idx]));
            }
    }
}

// ---------------------------------------------------------------------------
// Kernel 3: 3x3 conv + BN + ReLU. Block = (batch, output row h), 256 threads:
// thread = (w, oc-half). 3 input rows x 64 ch staged in LDS (bf16, 48KB).
// Weights from WT1[c*9+dy*3+dx][o] via wave-uniform scalar loads.
// ---------------------------------------------------------------------------
__global__ __launch_bounds__(256) void conv3_kernel(
    const unsigned short* __restrict__ y, const float* __restrict__ wt1,
    const float* __restrict__ beta1, unsigned short* __restrict__ y2)
{
    __shared__ unsigned short xs[3][64][128];   // 48 KB
    int b = blockIdx.x >> 7, h = blockIdx.x & 127;
    int t = threadIdx.x;
    const unsigned short* yb = y + b * CHW;
    for (int idx = t; idx < 3 * 64 * 128; idx += 256) {
        int dy = idx >> 13;
        int c = (idx >> 7) & 63;
        int ww = idx & 127;
        int hh = h + dy - 1;
        xs[dy][c][ww] = (hh >= 0 && hh < 128) ? yb[c * HW + hh * 128 + ww]
                                              : (unsigned short)0;
    }
    __syncthreads();

    int w = t & 127;
    int hfu = __builtin_amdgcn_readfirstlane(t >> 7);   // wave-uniform oc-half
    const float* wb = wt1 + hfu * 32;
    float acc[32];
    #pragma unroll
    for (int o = 0; o < 32; ++o) acc[o] = 0.f;

    for (int c = 0; c < 64; ++c) {
        #pragma unroll
        for (int dy = 0; dy < 3; ++dy) {
            float x0 = b2f(xs[dy][c][w]);
            float xl = (w > 0)   ? b2f(xs[dy][c][w - 1]) : 0.f;
            float xr = (w < 127) ? b2f(xs[dy][c][w + 1]) : 0.f;
            const float* wr = wb + (c * 9 + dy * 3) * 64;
            #pragma unroll
            for (int o = 0; o < 32; ++o) acc[o] = fmaf(wr[o],       xl, acc[o]);
            #pragma unroll
            for (int o = 0; o < 32; ++o) acc[o] = fmaf(wr[64 + o],  x0, acc[o]);
            #pragma unroll
            for (int o = 0; o < 32; ++o) acc[o] = fmaf(wr[128 + o], xr, acc[o]);
        }
    }

    int obase = hfu * 32;
    int outIdx = b * CHW + h * 128 + w;
    #pragma unroll
    for (int o = 0; o < 32; ++o) {
        float z = acc[o] + beta1[obase + o];
        y2[outIdx + (obase + o) * HW] = f2b(fmaxf(z, 0.f));
    }
}

// ---------------------------------------------------------------------------
// Kernel 4: 1x1 conv + BN + ReLU -> d_out (f32)
// ---------------------------------------------------------------------------
__global__ __launch_bounds__(128) void conv1x1_kernel(
    const unsigned short* __restrict__ y2, const float* __restrict__ w2T,
    const float* __restrict__ beta2, float* __restrict__ out)
{
    __shared__ float ys[64][128];   // 32 KB
    int b = blockIdx.x >> 7;
    int posBase = (blockIdx.x & 127) << 7;
    int t = threadIdx.x;
    int base = b * CHW + posBase;
    for (int c = 0; c < 64; ++c) ys[c][t] = b2f(y2[base + c * HW + t]);
    __syncthreads();

    float acc[64];
    #pragma unroll
    for (int o = 0; o < 64; ++o) acc[o] = 0.f;
    for (int c = 0; c < 64; ++c) {
        float yv = ys[c][t];
        const float* wr = w2T + c * 64;   // wave-uniform, inv2 folded
        #pragma unroll
        for (int o = 0; o < 64; ++o) acc[o] = fmaf(wr[o], yv, acc[o]);
    }
    for (int o = 0; o < 64; ++o)
        out[base + o * HW + t] = fmaxf(acc[o] + beta2[o], 0.f);
}

// ---------------------------------------------------------------------------
extern "C" void kernel_launch(void* const* d_in, const int* in_sizes, int n_in,
                              void* d_out, int out_size, void* d_ws, size_t ws_size,
                              hipStream_t stream)
{
    const float* x1   = (const float*)d_in[0];
    const float* xc   = (const float*)d_in[1];
    const float* Wq   = (const float*)d_in[2];
    const float* bq   = (const float*)d_in[3];
    const float* Wk   = (const float*)d_in[4];
    const float* bk   = (const float*)d_in[5];
    const float* Wv   = (const float*)d_in[6];
    const float* bv   = (const float*)d_in[7];
    const float* gam  = (const float*)d_in[8];
    const float* c1w  = (const float*)d_in[9];
    const float* bn1s = (const float*)d_in[10];
    const float* bn1b = (const float*)d_in[11];
    const float* bn1m = (const float*)d_in[12];
    const float* bn1v = (const float*)d_in[13];
    const float* c2w  = (const float*)d_in[14];
    const float* bn2s = (const float*)d_in[15];
    const float* bn2b = (const float*)d_in[16];
    const float* bn2m = (const float*)d_in[17];
    const float* bn2v = (const float*)d_in[18];
    float* out = (float*)d_out;

    char* ws = (char*)d_ws;
    const size_t BUF = 16777216;   // one bf16 [B,C,H,W] buffer
    unsigned short* qb  = (unsigned short*)(ws);
    unsigned short* kb  = (unsigned short*)(ws + BUF);
    unsigned short* vb  = (unsigned short*)(ws + 2 * BUF);
    unsigned short* yb  = (unsigned short*)(ws + 3 * BUF);
    unsigned short* y2b = (unsigned short*)(ws + 4 * BUF);
    float* wqT   = (float*)(ws + 5 * BUF);
    float* wkT   = wqT + 4096;
    float* wvT   = wkT + 4096;
    float* wt1   = wvT + 4096;     // 36864 f32
    float* w2T   = wt1 + 36864;
    float* beta1 = w2T + 4096;
    float* beta2 = beta1 + 64;

    prep_kernel<<<209, 256, 0, stream>>>(Wq, Wk, Wv, c1w, bn1s, bn1b, bn1m, bn1v,
                                         c2w, bn2s, bn2b, bn2m, bn2v,
                                         wqT, wkT, wvT, wt1, w2T, beta1, beta2);
    qkv_kernel<<<1024, 128, 0, stream>>>(x1, xc, wqT, wkT, wvT, bq, bk, bv,
                                         qb, kb, vb);
    hipFuncSetAttribute((const void*)attn_kernel,
                        hipFuncAttributeMaxDynamicSharedMemorySize, 131584);
    attn_kernel<<<512, 256, 131584, stream>>>(qb, kb, vb, xc, gam, yb);
    conv3_kernel<<<1024, 256, 0, stream>>>(yb, wt1, beta1, y2b);
    conv1x1_kernel<<<1024, 128, 0, stream>>>(y2b, w2T, beta2, out);
}

// Round 3
// 296.743 us; speedup vs baseline: 2.2960x; 2.2960x over previous
//
#include <hip/hip_runtime.h>

#define HW    16384
#define CHW   1048576
#define EPSV  1e-5f
#define PITCH 68          // rows with K=64 contraction (+4 pad)
#define APITCH 132        // attention rows, K=128 contraction (+4 pad)

typedef short bf16x8 __attribute__((ext_vector_type(8)));
typedef float f32x4 __attribute__((ext_vector_type(4)));
typedef unsigned short u16x4 __attribute__((ext_vector_type(4)));

static __device__ __forceinline__ unsigned short f2b(float f) {
    union { float f; unsigned int i; } x; x.f = f;
    unsigned int i = x.i + 0x7fffu + ((x.i >> 16) & 1u);   // RNE
    return (unsigned short)(i >> 16);
}

// 8 consecutive bf16 from LDS (8B-aligned) as an MFMA operand fragment
static __device__ __forceinline__ bf16x8 frag_load(const unsigned short* p) {
    union { u16x4 h[2]; bf16x8 v; } u;
    u.h[0] = *(const u16x4*)(p);
    u.h[1] = *(const u16x4*)(p + 4);
    return u.v;
}
static __device__ __forceinline__ f32x4 mfma16(bf16x8 a, bf16x8 b, f32x4 c) {
    return __builtin_amdgcn_mfma_f32_16x16x32_bf16(a, b, c, 0, 0, 0);
}

// ---------------------------------------------------------------------------
// Kernel 0: weight prep (bf16 conversion + BN folding)
// ---------------------------------------------------------------------------
__global__ void prep_kernel(const float* __restrict__ Wq, const float* __restrict__ Wk,
                            const float* __restrict__ Wv,
                            const float* __restrict__ c1w,
                            const float* __restrict__ bn1s, const float* __restrict__ bn1b,
                            const float* __restrict__ bn1m, const float* __restrict__ bn1v,
                            const float* __restrict__ c2w,
                            const float* __restrict__ bn2s, const float* __restrict__ bn2b,
                            const float* __restrict__ bn2m, const float* __restrict__ bn2v,
                            unsigned short* __restrict__ Wqb, unsigned short* __restrict__ Wkb,
                            unsigned short* __restrict__ Wvb, unsigned short* __restrict__ W3b,
                            unsigned short* __restrict__ W2b, float* __restrict__ beta1,
                            float* __restrict__ beta2)
{
    int i = blockIdx.x * blockDim.x + threadIdx.x;
    if (i < 12288) {                                  // QKV weights: elementwise bf16
        int mat = i >> 12, r = i & 4095;
        const float* src = (mat == 0) ? Wq : ((mat == 1) ? Wk : Wv);
        unsigned short* dst = (mat == 0) ? Wqb : ((mat == 1) ? Wkb : Wvb);
        dst[r] = f2b(src[r]);
    } else if (i < 49152) {                           // conv1 3x3 folded
        int j = i - 12288;
        int dydx = j >> 12, r = j & 4095, o = r >> 6, c = r & 63;
        float inv = bn1s[o] * rsqrtf(bn1v[o] + EPSV);
        W3b[j] = f2b(c1w[o * 576 + c * 9 + dydx] * inv);
    } else if (i < 53248) {                           // conv2 1x1 folded
        int r = i - 49152, o = r >> 6;
        float inv = bn2s[o] * rsqrtf(bn2v[o] + EPSV);
        W2b[r] = f2b(c2w[r] * inv);
    } else if (i < 53376) {
        int j = i - 53248;
        if (j < 64) {
            float inv = bn1s[j] * rsqrtf(bn1v[j] + EPSV);
            beta1[j] = bn1b[j] - bn1m[j] * inv;
        } else {
            int o = j - 64;
            float inv = bn2s[o] * rsqrtf(bn2v[o] + EPSV);
            beta2[o] = bn2b[o] - bn2m[o] * inv;
        }
    }
}

// ---------------------------------------------------------------------------
// Kernel 1: fused Q/K/V 1x1 projections via MFMA (K = 64, PITCH = 68 OK).
// ---------------------------------------------------------------------------
__global__ __launch_bounds__(256) void qkv_kernel(
    const float* __restrict__ x1, const float* __restrict__ xc,
    const unsigned short* __restrict__ Wqb, const unsigned short* __restrict__ Wkb,
    const unsigned short* __restrict__ Wvb,
    const float* __restrict__ bq, const float* __restrict__ bk,
    const float* __restrict__ bv,
    unsigned short* __restrict__ qo, unsigned short* __restrict__ ko,
    unsigned short* __restrict__ vo)
{
    __shared__ __align__(16) unsigned short WL[3][64][PITCH];
    __shared__ __align__(16) unsigned short XT[2][128][PITCH];
    int t = threadIdx.x;
    int b = blockIdx.x >> 7;
    int p0 = (blockIdx.x & 127) << 7;

    for (int idx = t; idx < 3 * 64 * 16; idx += 256) {
        int mat = idx >> 10, o = (idx >> 4) & 63, q4 = (idx & 15) << 2;
        const unsigned short* src = (mat == 0) ? Wqb : ((mat == 1) ? Wkb : Wvb);
        *(u16x4*)&WL[mat][o][q4] = *(const u16x4*)&src[o * 64 + q4];
    }
    const float* xs1 = x1 + b * CHW + p0;
    const float* xs2 = xc + b * CHW + p0;
    for (int idx = t; idx < 4096; idx += 256) {
        int c0 = (idx >> 7) << 1, p = idx & 127;
        unsigned int a0 = f2b(xs1[c0 * HW + p]);
        unsigned int a1 = f2b(xs1[(c0 + 1) * HW + p]);
        *(unsigned int*)&XT[0][p][c0] = a0 | (a1 << 16);
        unsigned int b0 = f2b(xs2[c0 * HW + p]);
        unsigned int b1 = f2b(xs2[(c0 + 1) * HW + p]);
        *(unsigned int*)&XT[1][p][c0] = b0 | (b1 << 16);
    }
    __syncthreads();

    int lane = t & 63, wid = t >> 6;
    int i16 = lane & 15;
    int g8 = (lane >> 4) << 3;
    int g4 = (lane >> 4) << 2;
    int n0 = wid << 5;

    bf16x8 bfr[2][2][2];
    #pragma unroll
    for (int inp = 0; inp < 2; ++inp)
        #pragma unroll
        for (int nt = 0; nt < 2; ++nt)
            #pragma unroll
            for (int ks = 0; ks < 2; ++ks)
                bfr[inp][nt][ks] = frag_load(&XT[inp][n0 + nt * 16 + i16][ks * 32 + g8]);

    f32x4 zz = {0.f, 0.f, 0.f, 0.f};
    f32x4 acc[3][4][2];
    #pragma unroll
    for (int mat = 0; mat < 3; ++mat)
        #pragma unroll
        for (int m = 0; m < 4; ++m) { acc[mat][m][0] = zz; acc[mat][m][1] = zz; }

    #pragma unroll
    for (int mat = 0; mat < 3; ++mat) {
        const int inp = (mat == 0) ? 0 : 1;
        #pragma unroll
        for (int ks = 0; ks < 2; ++ks)
            #pragma unroll
            for (int m = 0; m < 4; ++m) {
                bf16x8 af = frag_load(&WL[mat][m * 16 + i16][ks * 32 + g8]);
                acc[mat][m][0] = mfma16(af, bfr[inp][0][ks], acc[mat][m][0]);
                acc[mat][m][1] = mfma16(af, bfr[inp][1][ks], acc[mat][m][1]);
            }
    }

    #pragma unroll
    for (int mat = 0; mat < 3; ++mat) {
        unsigned short* dst = ((mat == 0) ? qo : ((mat == 1) ? ko : vo)) + b * CHW + p0;
        const float* bias = (mat == 0) ? bq : ((mat == 1) ? bk : bv);
        #pragma unroll
        for (int m = 0; m < 4; ++m)
            #pragma unroll
            for (int r = 0; r < 4; ++r) {
                int o = m * 16 + g4 + r;
                float bb = bias[o];
                dst[o * HW + n0 + i16]      = f2b(acc[mat][m][0][r] + bb);
                dst[o * HW + n0 + 16 + i16] = f2b(acc[mat][m][1][r] + bb);
            }
    }
}

// ---------------------------------------------------------------------------
// Kernel 2: attention per (b,c), full MFMA. Contraction K = 128 -> rows must
// hold 128 elements: APITCH = 132 (was the round-1 OOB bug with PITCH=68).
// Dynamic LDS: QT,KT,VL [128][132] bf16 = 101376 B; PL aliases dead QT.
// ---------------------------------------------------------------------------
__global__ __launch_bounds__(256) void attn_kernel(
    const unsigned short* __restrict__ q, const unsigned short* __restrict__ k,
    const unsigned short* __restrict__ v, const float* __restrict__ xc,
    const float* __restrict__ gamma_p, unsigned short* __restrict__ y)
{
    extern __shared__ __align__(16) unsigned short sarena[];
    unsigned short (*QT)[APITCH] = (unsigned short(*)[APITCH])sarena;
    unsigned short (*KT)[APITCH] = (unsigned short(*)[APITCH])(sarena + 16896);
    unsigned short (*VL)[APITCH] = (unsigned short(*)[APITCH])(sarena + 33792);
    unsigned short (*PL)[APITCH] = QT;      // aliases QT after phase 1

    int t = threadIdx.x;
    int base = blockIdx.x * HW;

    for (int idx = t; idx < 8192; idx += 256) {               // transpose Q,K
        int h0 = (idx >> 7) << 1, w = idx & 127;
        unsigned int q0 = q[base + h0 * 128 + w];
        unsigned int q1 = q[base + (h0 + 1) * 128 + w];
        *(unsigned int*)&QT[w][h0] = q0 | (q1 << 16);
        unsigned int k0 = k[base + h0 * 128 + w];
        unsigned int k1 = k[base + (h0 + 1) * 128 + w];
        *(unsigned int*)&KT[w][h0] = k0 | (k1 << 16);
    }
    for (int idx = t; idx < 4096; idx += 256) {               // copy V natural
        int h = idx >> 5, q4 = (idx & 31) << 2;
        *(u16x4*)&VL[h][q4] = *(const u16x4*)&v[base + h * 128 + q4];
    }
    __syncthreads();

    int lane = t & 63, wid = t >> 6;
    int i16 = lane & 15;
    int g8 = (lane >> 4) << 3;
    int g4 = (lane >> 4) << 2;
    int m0 = wid << 5;

    f32x4 zz = {0.f, 0.f, 0.f, 0.f};
    f32x4 e[2][8];
    #pragma unroll
    for (int mi = 0; mi < 2; ++mi)
        #pragma unroll
        for (int nt = 0; nt < 8; ++nt) e[mi][nt] = zz;

    #pragma unroll
    for (int ks = 0; ks < 4; ++ks) {
        bf16x8 a0 = frag_load(&KT[m0 + i16][ks * 32 + g8]);
        bf16x8 a1 = frag_load(&KT[m0 + 16 + i16][ks * 32 + g8]);
        #pragma unroll
        for (int nt = 0; nt < 8; ++nt) {
            bf16x8 bfq = frag_load(&QT[nt * 16 + i16][ks * 32 + g8]);
            e[0][nt] = mfma16(a0, bfq, e[0][nt]);
            e[1][nt] = mfma16(a1, bfq, e[1][nt]);
        }
    }
    __syncthreads();   // QT/KT reads complete; QT region becomes PL

    // softmax over w (cols of eT): reduce across nt and the 16-lane group
    #pragma unroll
    for (int mi = 0; mi < 2; ++mi) {
        #pragma unroll
        for (int r = 0; r < 4; ++r) {
            float mx = e[mi][0][r];
            #pragma unroll
            for (int nt = 1; nt < 8; ++nt) mx = fmaxf(mx, e[mi][nt][r]);
            mx = fmaxf(mx, __shfl_xor(mx, 1));
            mx = fmaxf(mx, __shfl_xor(mx, 2));
            mx = fmaxf(mx, __shfl_xor(mx, 4));
            mx = fmaxf(mx, __shfl_xor(mx, 8));
            float pv[8];
            float s = 0.f;
            #pragma unroll
            for (int nt = 0; nt < 8; ++nt) {
                pv[nt] = __expf(e[mi][nt][r] - mx);
                s += pv[nt];
            }
            s += __shfl_xor(s, 1);
            s += __shfl_xor(s, 2);
            s += __shfl_xor(s, 4);
            s += __shfl_xor(s, 8);
            float rinv = 1.f / s;
            int vr = m0 + mi * 16 + g4 + r;
            #pragma unroll
            for (int nt = 0; nt < 8; ++nt)
                PL[vr][nt * 16 + i16] = f2b(pv[nt] * rinv);
        }
    }
    __syncthreads();

    f32x4 o_[2][8];
    #pragma unroll
    for (int mi = 0; mi < 2; ++mi)
        #pragma unroll
        for (int nt = 0; nt < 8; ++nt) o_[mi][nt] = zz;

    #pragma unroll
    for (int ks = 0; ks < 4; ++ks) {
        bf16x8 a0 = frag_load(&VL[m0 + i16][ks * 32 + g8]);
        bf16x8 a1 = frag_load(&VL[m0 + 16 + i16][ks * 32 + g8]);
        #pragma unroll
        for (int nt = 0; nt < 8; ++nt) {
            bf16x8 bp = frag_load(&PL[nt * 16 + i16][ks * 32 + g8]);
            o_[0][nt] = mfma16(a0, bp, o_[0][nt]);
            o_[1][nt] = mfma16(a1, bp, o_[1][nt]);
        }
    }

    float g = gamma_p[0];
    const float* xcb = xc + base;
    #pragma unroll
    for (int mi = 0; mi < 2; ++mi)
        #pragma unroll
        for (int nt = 0; nt < 8; ++nt)
            #pragma unroll
            for (int r = 0; r < 4; ++r) {
                int hh = m0 + mi * 16 + g4 + r;
                int ww = nt * 16 + i16;
                int idx = hh * 128 + ww;
                y[base + idx] = f2b(fmaf(g, o_[mi][nt][r], xcb[idx]));
            }
}

// ---------------------------------------------------------------------------
// Kernel 3: 3x3 conv + BN + ReLU + 1x1 conv + BN + ReLU, fused, MFMA (K=64).
// Dynamic LDS 157760 B: W3 [9][64][68] | W2 [64][68] | XT [4][130][68]
// (Y2 [256][68] aliases XT).
// ---------------------------------------------------------------------------
__global__ __launch_bounds__(256) void conv3_fused_kernel(
    const unsigned short* __restrict__ yin, const unsigned short* __restrict__ W3b,
    const unsigned short* __restrict__ W2b, const float* __restrict__ beta1,
    const float* __restrict__ beta2, float* __restrict__ out)
{
    extern __shared__ __align__(16) unsigned short arena[];
    unsigned short* W3 = arena;              // 39168 shorts
    unsigned short* W2 = arena + 39168;      // 4352 shorts
    unsigned short* XT = arena + 43520;      // 4*130*68 = 35360 shorts
    unsigned short* Y2 = arena + 43520;      // alias (XT dead by then)

    int t = threadIdx.x;
    int b = blockIdx.x >> 6;
    int h0 = (blockIdx.x & 63) << 1;

    for (int idx = t; idx < 10240; idx += 256) {
        if (idx < 9216) {
            int dydx = idx >> 10, o = (idx >> 4) & 63, q4 = (idx & 15) << 2;
            *(u16x4*)&W3[(dydx * 64 + o) * PITCH + q4] =
                *(const u16x4*)&W3b[dydx * 4096 + o * 64 + q4];
        } else {
            int j = idx - 9216;
            int o = j >> 4, q4 = (j & 15) << 2;
            *(u16x4*)&W2[o * PITCH + q4] = *(const u16x4*)&W2b[o * 64 + q4];
        }
    }
    u16x4 z4 = {0, 0, 0, 0};
    if (t < 136) {                                    // zero w-halo rows 0,129
        int dy = t / 34, rr = t % 34;
        int row = (rr < 17) ? 0 : 129;
        int q4 = (rr % 17) << 2;
        *(u16x4*)&XT[(dy * 130 + row) * PITCH + q4] = z4;
    }
    const unsigned short* yb = yin + b * CHW;
    for (int idx = t; idx < 16384; idx += 256) {      // 4 planes, c-pairs
        int dy = idx >> 12, c0 = ((idx >> 7) & 31) << 1, w = idx & 127;
        int hh = h0 + dy - 1;
        unsigned int val = 0;
        if (hh >= 0 && hh < 128) {
            unsigned int a0 = yb[c0 * HW + hh * 128 + w];
            unsigned int a1 = yb[(c0 + 1) * HW + hh * 128 + w];
            val = a0 | (a1 << 16);
        }
        *(unsigned int*)&XT[(dy * 130 + w + 1) * PITCH + c0] = val;
    }
    __syncthreads();

    int lane = t & 63, wid = t >> 6;
    int i16 = lane & 15;
    int g8 = (lane >> 4) << 3;
    int g4 = (lane >> 4) << 2;
    int orow = wid >> 1;               // which of the 2 output rows
    int wbase = (wid & 1) << 6;        // 64-wide half of the row

    f32x4 zz = {0.f, 0.f, 0.f, 0.f};
    f32x4 acc[4][4];
    #pragma unroll
    for (int m = 0; m < 4; ++m)
        #pragma unroll
        for (int nt = 0; nt < 4; ++nt) acc[m][nt] = zz;

    #pragma unroll
    for (int dy = 0; dy < 3; ++dy)
        #pragma unroll
        for (int dx = 0; dx < 3; ++dx) {
            const unsigned short* wpl = W3 + (dy * 3 + dx) * 64 * PITCH;
            const unsigned short* xpl = XT + ((dy + orow) * 130 + dx) * PITCH;
            #pragma unroll
            for (int ks = 0; ks < 2; ++ks) {
                bf16x8 bf0 = frag_load(xpl + (wbase + i16) * PITCH + ks * 32 + g8);
                bf16x8 bf1 = frag_load(xpl + (wbase + 16 + i16) * PITCH + ks * 32 + g8);
                bf16x8 bf2 = frag_load(xpl + (wbase + 32 + i16) * PITCH + ks * 32 + g8);
                bf16x8 bf3 = frag_load(xpl + (wbase + 48 + i16) * PITCH + ks * 32 + g8);
                #pragma unroll
                for (int m = 0; m < 4; ++m) {
                    bf16x8 a = frag_load(wpl + (m * 16 + i16) * PITCH + ks * 32 + g8);
                    acc[m][0] = mfma16(a, bf0, acc[m][0]);
                    acc[m][1] = mfma16(a, bf1, acc[m][1]);
                    acc[m][2] = mfma16(a, bf2, acc[m][2]);
                    acc[m][3] = mfma16(a, bf3, acc[m][3]);
                }
            }
        }
    __syncthreads();   // all XT reads done before aliasing as Y2

    #pragma unroll
    for (int m = 0; m < 4; ++m) {
        float b0 = beta1[m * 16 + g4 + 0];
        float b1 = beta1[m * 16 + g4 + 1];
        float b2 = beta1[m * 16 + g4 + 2];
        float b3 = beta1[m * 16 + g4 + 3];
        #pragma unroll
        for (int nt = 0; nt < 4; ++nt) {
            int p = orow * 128 + wbase + nt * 16 + i16;
            u16x4 pk;
            pk[0] = f2b(fmaxf(acc[m][nt][0] + b0, 0.f));
            pk[1] = f2b(fmaxf(acc[m][nt][1] + b1, 0.f));
            pk[2] = f2b(fmaxf(acc[m][nt][2] + b2, 0.f));
            pk[3] = f2b(fmaxf(acc[m][nt][3] + b3, 0.f));
            *(u16x4*)&Y2[p * PITCH + m * 16 + g4] = pk;
        }
    }
    __syncthreads();

    f32x4 acc2[4][4];
    #pragma unroll
    for (int m = 0; m < 4; ++m)
        #pragma unroll
        for (int nt = 0; nt < 4; ++nt) acc2[m][nt] = zz;

    #pragma unroll
    for (int ks = 0; ks < 2; ++ks) {
        bf16x8 bf0 = frag_load(Y2 + (orow * 128 + wbase + i16) * PITCH + ks * 32 + g8);
        bf16x8 bf1 = frag_load(Y2 + (orow * 128 + wbase + 16 + i16) * PITCH + ks * 32 + g8);
        bf16x8 bf2 = frag_load(Y2 + (orow * 128 + wbase + 32 + i16) * PITCH + ks * 32 + g8);
        bf16x8 bf3 = frag_load(Y2 + (orow * 128 + wbase + 48 + i16) * PITCH + ks * 32 + g8);
        #pragma unroll
        for (int m = 0; m < 4; ++m) {
            bf16x8 a = frag_load(W2 + (m * 16 + i16) * PITCH + ks * 32 + g8);
            acc2[m][0] = mfma16(a, bf0, acc2[m][0]);
            acc2[m][1] = mfma16(a, bf1, acc2[m][1]);
            acc2[m][2] = mfma16(a, bf2, acc2[m][2]);
            acc2[m][3] = mfma16(a, bf3, acc2[m][3]);
        }
    }

    float* ob = out + b * CHW + (h0 + orow) * 128 + wbase;
    #pragma unroll
    for (int m = 0; m < 4; ++m)
        #pragma unroll
        for (int r = 0; r < 4; ++r) {
            int o = m * 16 + g4 + r;
            float bt = beta2[o];
            #pragma unroll
            for (int nt = 0; nt < 4; ++nt)
                ob[o * HW + nt * 16 + i16] = fmaxf(acc2[m][nt][r] + bt, 0.f);
        }
}

// ---------------------------------------------------------------------------
extern "C" void kernel_launch(void* const* d_in, const int* in_sizes, int n_in,
                              void* d_out, int out_size, void* d_ws, size_t ws_size,
                              hipStream_t stream)
{
    const float* x1   = (const float*)d_in[0];
    const float* xc   = (const float*)d_in[1];
    const float* Wq   = (const float*)d_in[2];
    const float* bq   = (const float*)d_in[3];
    const float* Wk   = (const float*)d_in[4];
    const float* bk   = (const float*)d_in[5];
    const float* Wv   = (const float*)d_in[6];
    const float* bv   = (const float*)d_in[7];
    const float* gam  = (const float*)d_in[8];
    const float* c1w  = (const float*)d_in[9];
    const float* bn1s = (const float*)d_in[10];
    const float* bn1b = (const float*)d_in[11];
    const float* bn1m = (const float*)d_in[12];
    const float* bn1v = (const float*)d_in[13];
    const float* c2w  = (const float*)d_in[14];
    const float* bn2s = (const float*)d_in[15];
    const float* bn2b = (const float*)d_in[16];
    const float* bn2m = (const float*)d_in[17];
    const float* bn2v = (const float*)d_in[18];
    float* out = (float*)d_out;

    char* ws = (char*)d_ws;
    const size_t BUF = 16777216;   // one bf16 [B,C,H,W] buffer
    unsigned short* qb  = (unsigned short*)(ws);
    unsigned short* kb  = (unsigned short*)(ws + BUF);
    unsigned short* vb  = (unsigned short*)(ws + 2 * BUF);
    unsigned short* yb  = (unsigned short*)(ws + 3 * BUF);
    unsigned short* Wqb = (unsigned short*)(ws + 4 * BUF);
    unsigned short* Wkb = Wqb + 4096;
    unsigned short* Wvb = Wkb + 4096;
    unsigned short* W3b = Wvb + 4096;      // 36864 shorts
    unsigned short* W2b = W3b + 36864;     // 4096 shorts
    float* beta1 = (float*)(W2b + 4096);
    float* beta2 = beta1 + 64;

    prep_kernel<<<209, 256, 0, stream>>>(Wq, Wk, Wv, c1w, bn1s, bn1b, bn1m, bn1v,
                                         c2w, bn2s, bn2b, bn2m, bn2v,
                                         Wqb, Wkb, Wvb, W3b, W2b, beta1, beta2);
    qkv_kernel<<<1024, 256, 0, stream>>>(x1, xc, Wqb, Wkb, Wvb, bq, bk, bv,
                                         qb, kb, vb);
    hipFuncSetAttribute((const void*)attn_kernel,
                        hipFuncAttributeMaxDynamicSharedMemorySize, 101376);
    attn_kernel<<<512, 256, 101376, stream>>>(qb, kb, vb, xc, gam, yb);
    hipFuncSetAttribute((const void*)conv3_fused_kernel,
                        hipFuncAttributeMaxDynamicSharedMemorySize, 157760);
    conv3_fused_kernel<<<512, 256, 157760, stream>>>(yb, W3b, W2b, beta1, beta2, out);
}

// Round 4
// 217.167 us; speedup vs baseline: 3.1373x; 1.3664x over previous
//
#include <hip/hip_runtime.h>

#define HW    16384
#define CHW   1048576
#define EPSV  1e-5f
#define PITCH 68          // rows with K=64 contraction (+4 pad)
#define APITCH 132        // attention rows, K=128 contraction (+4 pad)

typedef short bf16x8 __attribute__((ext_vector_type(8)));
typedef float f32x4 __attribute__((ext_vector_type(4)));
typedef unsigned short u16x4 __attribute__((ext_vector_type(4)));

static __device__ __forceinline__ unsigned short f2b(float f) {
    union { float f; unsigned int i; } x; x.f = f;
    unsigned int i = x.i + 0x7fffu + ((x.i >> 16) & 1u);   // RNE
    return (unsigned short)(i >> 16);
}

// 8 consecutive bf16 (16B-aligned) as an MFMA operand fragment
static __device__ __forceinline__ bf16x8 frag_load(const unsigned short* p) {
    union { u16x4 h[2]; bf16x8 v; } u;
    u.h[0] = *(const u16x4*)(p);
    u.h[1] = *(const u16x4*)(p + 4);
    return u.v;
}
static __device__ __forceinline__ bf16x8 gfrag(const unsigned short* p) {
    return *(const bf16x8*)p;   // 16B-aligned global load (dwordx4)
}
static __device__ __forceinline__ f32x4 mfma16(bf16x8 a, bf16x8 b, f32x4 c) {
    return __builtin_amdgcn_mfma_f32_16x16x32_bf16(a, b, c, 0, 0, 0);
}

// ---------------------------------------------------------------------------
// Kernel 0: weight prep (bf16 conversion + BN folding)
// ---------------------------------------------------------------------------
__global__ void prep_kernel(const float* __restrict__ Wq, const float* __restrict__ Wk,
                            const float* __restrict__ Wv,
                            const float* __restrict__ c1w,
                            const float* __restrict__ bn1s, const float* __restrict__ bn1b,
                            const float* __restrict__ bn1m, const float* __restrict__ bn1v,
                            const float* __restrict__ c2w,
                            const float* __restrict__ bn2s, const float* __restrict__ bn2b,
                            const float* __restrict__ bn2m, const float* __restrict__ bn2v,
                            unsigned short* __restrict__ Wqb, unsigned short* __restrict__ Wkb,
                            unsigned short* __restrict__ Wvb, unsigned short* __restrict__ W3b,
                            unsigned short* __restrict__ W2b, float* __restrict__ beta1,
                            float* __restrict__ beta2)
{
    int i = blockIdx.x * blockDim.x + threadIdx.x;
    if (i < 12288) {                                  // QKV weights: elementwise bf16
        int mat = i >> 12, r = i & 4095;
        const float* src = (mat == 0) ? Wq : ((mat == 1) ? Wk : Wv);
        unsigned short* dst = (mat == 0) ? Wqb : ((mat == 1) ? Wkb : Wvb);
        dst[r] = f2b(src[r]);
    } else if (i < 49152) {                           // conv1 3x3 folded
        int j = i - 12288;
        int dydx = j >> 12, r = j & 4095, o = r >> 6, c = r & 63;
        float inv = bn1s[o] * rsqrtf(bn1v[o] + EPSV);
        W3b[j] = f2b(c1w[o * 576 + c * 9 + dydx] * inv);
    } else if (i < 53248) {                           // conv2 1x1 folded
        int r = i - 49152, o = r >> 6;
        float inv = bn2s[o] * rsqrtf(bn2v[o] + EPSV);
        W2b[r] = f2b(c2w[r] * inv);
    } else if (i < 53376) {
        int j = i - 53248;
        if (j < 64) {
            float inv = bn1s[j] * rsqrtf(bn1v[j] + EPSV);
            beta1[j] = bn1b[j] - bn1m[j] * inv;
        } else {
            int o = j - 64;
            float inv = bn2s[o] * rsqrtf(bn2v[o] + EPSV);
            beta2[o] = bn2b[o] - bn2m[o] * inv;
        }
    }
}

// ---------------------------------------------------------------------------
// Kernel 1: fused Q/K/V 1x1 projections via MFMA. Weights read as fragments
// directly from global (L2-hot). LDS: only XT [2][128][68] = 34.8 KB
// -> 3-4 blocks/CU.
// ---------------------------------------------------------------------------
__global__ __launch_bounds__(256) void qkv_kernel(
    const float* __restrict__ x1, const float* __restrict__ xc,
    const unsigned short* __restrict__ Wqb, const unsigned short* __restrict__ Wkb,
    const unsigned short* __restrict__ Wvb,
    const float* __restrict__ bq, const float* __restrict__ bk,
    const float* __restrict__ bv,
    unsigned short* __restrict__ qo, unsigned short* __restrict__ ko,
    unsigned short* __restrict__ vo)
{
    __shared__ __align__(16) unsigned short XT[2][128][PITCH];
    int t = threadIdx.x;
    int b = blockIdx.x >> 7;
    int p0 = (blockIdx.x & 127) << 7;

    const float* xs1 = x1 + b * CHW + p0;
    const float* xs2 = xc + b * CHW + p0;
    for (int idx = t; idx < 2048; idx += 256) {     // 32 c-pairs x 64 p-pairs
        int c0 = ((idx >> 6) & 31) << 1, p2 = (idx & 63) << 1;
        float2 a0 = *(const float2*)&xs1[c0 * HW + p2];
        float2 a1 = *(const float2*)&xs1[(c0 + 1) * HW + p2];
        *(unsigned int*)&XT[0][p2][c0]     = f2b(a0.x) | ((unsigned int)f2b(a1.x) << 16);
        *(unsigned int*)&XT[0][p2 + 1][c0] = f2b(a0.y) | ((unsigned int)f2b(a1.y) << 16);
        float2 b0 = *(const float2*)&xs2[c0 * HW + p2];
        float2 b1 = *(const float2*)&xs2[(c0 + 1) * HW + p2];
        *(unsigned int*)&XT[1][p2][c0]     = f2b(b0.x) | ((unsigned int)f2b(b1.x) << 16);
        *(unsigned int*)&XT[1][p2 + 1][c0] = f2b(b0.y) | ((unsigned int)f2b(b1.y) << 16);
    }
    __syncthreads();

    int lane = t & 63, wid = t >> 6;
    int i16 = lane & 15;
    int g8 = (lane >> 4) << 3;
    int g4 = (lane >> 4) << 2;
    int n0 = wid << 5;

    bf16x8 bfr[2][2][2];
    #pragma unroll
    for (int inp = 0; inp < 2; ++inp)
        #pragma unroll
        for (int nt = 0; nt < 2; ++nt)
            #pragma unroll
            for (int ks = 0; ks < 2; ++ks)
                bfr[inp][nt][ks] = frag_load(&XT[inp][n0 + nt * 16 + i16][ks * 32 + g8]);

    f32x4 zz = {0.f, 0.f, 0.f, 0.f};
    f32x4 acc[3][4][2];
    #pragma unroll
    for (int mat = 0; mat < 3; ++mat)
        #pragma unroll
        for (int m = 0; m < 4; ++m) { acc[mat][m][0] = zz; acc[mat][m][1] = zz; }

    #pragma unroll
    for (int mat = 0; mat < 3; ++mat) {
        const unsigned short* Wmat = (mat == 0) ? Wqb : ((mat == 1) ? Wkb : Wvb);
        const int inp = (mat == 0) ? 0 : 1;
        #pragma unroll
        for (int ks = 0; ks < 2; ++ks)
            #pragma unroll
            for (int m = 0; m < 4; ++m) {
                bf16x8 af = gfrag(Wmat + (m * 16 + i16) * 64 + ks * 32 + g8);
                acc[mat][m][0] = mfma16(af, bfr[inp][0][ks], acc[mat][m][0]);
                acc[mat][m][1] = mfma16(af, bfr[inp][1][ks], acc[mat][m][1]);
            }
    }

    #pragma unroll
    for (int mat = 0; mat < 3; ++mat) {
        unsigned short* dst = ((mat == 0) ? qo : ((mat == 1) ? ko : vo)) + b * CHW + p0;
        const float* bias = (mat == 0) ? bq : ((mat == 1) ? bk : bv);
        #pragma unroll
        for (int m = 0; m < 4; ++m)
            #pragma unroll
            for (int r = 0; r < 4; ++r) {
                int o = m * 16 + g4 + r;
                float bb = bias[o];
                dst[o * HW + n0 + i16]      = f2b(acc[mat][m][0][r] + bb);
                dst[o * HW + n0 + 16 + i16] = f2b(acc[mat][m][1][r] + bb);
            }
    }
}

// ---------------------------------------------------------------------------
// Kernel 2: attention per (b,c), 512 threads / 8 waves, each wave owns 16
// v-rows. V fragments read directly from global (each element used once).
// Dynamic LDS: QT,KT [128][132] bf16 = 67584 B -> 2 blocks/CU (16 waves).
// ---------------------------------------------------------------------------
__global__ __launch_bounds__(512) void attn_kernel(
    const unsigned short* __restrict__ q, const unsigned short* __restrict__ k,
    const unsigned short* __restrict__ v, const float* __restrict__ xc,
    const float* __restrict__ gamma_p, unsigned short* __restrict__ y)
{
    extern __shared__ __align__(16) unsigned short sarena[];
    unsigned short (*QT)[APITCH] = (unsigned short(*)[APITCH])sarena;
    unsigned short (*KT)[APITCH] = (unsigned short(*)[APITCH])(sarena + 16896);
    unsigned short (*PL)[APITCH] = QT;      // aliases QT after phase 1

    int t = threadIdx.x;
    int base = blockIdx.x * HW;

    for (int idx = t; idx < 4096; idx += 512) {    // 64 h-pairs x 64 w-pairs
        int h0 = (idx >> 6) << 1, w2 = (idx & 63) << 1;
        unsigned int q0 = *(const unsigned int*)&q[base + h0 * 128 + w2];
        unsigned int q1 = *(const unsigned int*)&q[base + (h0 + 1) * 128 + w2];
        *(unsigned int*)&QT[w2][h0]     = (q0 & 0xffffu) | (q1 << 16);
        *(unsigned int*)&QT[w2 + 1][h0] = (q0 >> 16) | (q1 & 0xffff0000u);
        unsigned int k0 = *(const unsigned int*)&k[base + h0 * 128 + w2];
        unsigned int k1 = *(const unsigned int*)&k[base + (h0 + 1) * 128 + w2];
        *(unsigned int*)&KT[w2][h0]     = (k0 & 0xffffu) | (k1 << 16);
        *(unsigned int*)&KT[w2 + 1][h0] = (k0 >> 16) | (k1 & 0xffff0000u);
    }
    __syncthreads();

    int lane = t & 63, wid = t >> 6;
    int i16 = lane & 15;
    int g8 = (lane >> 4) << 3;
    int g4 = (lane >> 4) << 2;
    int m0 = wid << 4;               // 16 v-rows per wave

    f32x4 zz = {0.f, 0.f, 0.f, 0.f};
    f32x4 e[8];
    #pragma unroll
    for (int nt = 0; nt < 8; ++nt) e[nt] = zz;

    #pragma unroll
    for (int ks = 0; ks < 4; ++ks) {
        bf16x8 a0 = frag_load(&KT[m0 + i16][ks * 32 + g8]);
        #pragma unroll
        for (int nt = 0; nt < 8; ++nt) {
            bf16x8 bfq = frag_load(&QT[nt * 16 + i16][ks * 32 + g8]);
            e[nt] = mfma16(a0, bfq, e[nt]);
        }
    }
    __syncthreads();   // QT/KT reads complete; QT region becomes PL

    // softmax over w: reduce across nt (regs) and the 16-lane col group
    #pragma unroll
    for (int r = 0; r < 4; ++r) {
        float mx = e[0][r];
        #pragma unroll
        for (int nt = 1; nt < 8; ++nt) mx = fmaxf(mx, e[nt][r]);
        mx = fmaxf(mx, __shfl_xor(mx, 1));
        mx = fmaxf(mx, __shfl_xor(mx, 2));
        mx = fmaxf(mx, __shfl_xor(mx, 4));
        mx = fmaxf(mx, __shfl_xor(mx, 8));
        float pv[8];
        float s = 0.f;
        #pragma unroll
        for (int nt = 0; nt < 8; ++nt) {
            pv[nt] = __expf(e[nt][r] - mx);
            s += pv[nt];
        }
        s += __shfl_xor(s, 1);
        s += __shfl_xor(s, 2);
        s += __shfl_xor(s, 4);
        s += __shfl_xor(s, 8);
        float rinv = 1.f / s;
        int vr = m0 + g4 + r;
        #pragma unroll
        for (int nt = 0; nt < 8; ++nt)
            PL[vr][nt * 16 + i16] = f2b(pv[nt] * rinv);
    }
    __syncthreads();

    f32x4 o_[8];
    #pragma unroll
    for (int nt = 0; nt < 8; ++nt) o_[nt] = zz;

    const unsigned short* vb_ = v + base;
    #pragma unroll
    for (int ks = 0; ks < 4; ++ks) {
        bf16x8 a0 = gfrag(vb_ + (m0 + i16) * 128 + ks * 32 + g8);   // V direct
        #pragma unroll
        for (int nt = 0; nt < 8; ++nt) {
            bf16x8 bp = frag_load(&PL[nt * 16 + i16][ks * 32 + g8]);
            o_[nt] = mfma16(a0, bp, o_[nt]);
        }
    }

    float g = gamma_p[0];
    const float* xcb = xc + base;
    #pragma unroll
    for (int nt = 0; nt < 8; ++nt)
        #pragma unroll
        for (int r = 0; r < 4; ++r) {
            int hh = m0 + g4 + r;
            int ww = nt * 16 + i16;
            int idx = hh * 128 + ww;
            y[base + idx] = f2b(fmaf(g, o_[nt][r], xcb[idx]));
        }
}

// ---------------------------------------------------------------------------
// Kernel 3: 3x3 conv + BN + ReLU + 1x1 conv + BN + ReLU, fused, MFMA.
// 512 threads / 8 waves: wave = (orow, w-half, m-half). Weight fragments
// direct from global (L2-hot). Dynamic LDS 70720 B: XT [4][130][68]
// (Y2 [256][68] aliases XT) -> 2 blocks/CU (16 waves).
// ---------------------------------------------------------------------------
__global__ __launch_bounds__(512) void conv3_fused_kernel(
    const unsigned short* __restrict__ yin, const unsigned short* __restrict__ W3b,
    const unsigned short* __restrict__ W2b, const float* __restrict__ beta1,
    const float* __restrict__ beta2, float* __restrict__ out)
{
    extern __shared__ __align__(16) unsigned short arena[];
    unsigned short* XT = arena;              // 4*130*68 = 35360 shorts
    unsigned short* Y2 = arena;              // [256][68] alias (XT dead by then)

    int t = threadIdx.x;
    int b = blockIdx.x >> 6;
    int h0 = (blockIdx.x & 63) << 1;

    u16x4 z4 = {0, 0, 0, 0};
    if (t < 136) {                                    // zero w-halo rows 0,129
        int dy = t / 34, rr = t % 34;
        int row = (rr < 17) ? 0 : 129;
        int q4 = (rr % 17) << 2;
        *(u16x4*)&XT[(dy * 130 + row) * PITCH + q4] = z4;
    }
    const unsigned short* yb = yin + b * CHW;
    for (int idx = t; idx < 8192; idx += 512) {  // 4 planes x 32 c-pairs x 64 w-pairs
        int dy = idx >> 11, c0 = ((idx >> 6) & 31) << 1, w2 = (idx & 63) << 1;
        int hh = h0 + dy - 1;
        unsigned int a0 = 0, a1 = 0;
        if (hh >= 0 && hh < 128) {
            a0 = *(const unsigned int*)&yb[c0 * HW + hh * 128 + w2];
            a1 = *(const unsigned int*)&yb[(c0 + 1) * HW + hh * 128 + w2];
        }
        *(unsigned int*)&XT[(dy * 130 + w2 + 1) * PITCH + c0] = (a0 & 0xffffu) | (a1 << 16);
        *(unsigned int*)&XT[(dy * 130 + w2 + 2) * PITCH + c0] = (a0 >> 16) | (a1 & 0xffff0000u);
    }
    __syncthreads();

    int lane = t & 63, wid = t >> 6;
    int i16 = lane & 15;
    int g8 = (lane >> 4) << 3;
    int g4 = (lane >> 4) << 2;
    int orow  = wid >> 2;              // output row within pair
    int wbase = ((wid >> 1) & 1) << 6; // 64-wide half of the row
    int mbase = (wid & 1) << 1;        // 2 of the 4 m-tiles

    f32x4 zz = {0.f, 0.f, 0.f, 0.f};
    f32x4 acc[2][4];
    #pragma unroll
    for (int m = 0; m < 2; ++m)
        #pragma unroll
        for (int nt = 0; nt < 4; ++nt) acc[m][nt] = zz;

    #pragma unroll
    for (int dy = 0; dy < 3; ++dy)
        #pragma unroll
        for (int dx = 0; dx < 3; ++dx) {
            const unsigned short* wpl = W3b + (dy * 3 + dx) * 4096;
            const unsigned short* xpl = XT + ((dy + orow) * 130 + dx) * PITCH;
            #pragma unroll
            for (int ks = 0; ks < 2; ++ks) {
                bf16x8 bf0 = frag_load(xpl + (wbase + i16) * PITCH + ks * 32 + g8);
                bf16x8 bf1 = frag_load(xpl + (wbase + 16 + i16) * PITCH + ks * 32 + g8);
                bf16x8 bf2 = frag_load(xpl + (wbase + 32 + i16) * PITCH + ks * 32 + g8);
                bf16x8 bf3 = frag_load(xpl + (wbase + 48 + i16) * PITCH + ks * 32 + g8);
                #pragma unroll
                for (int m = 0; m < 2; ++m) {
                    bf16x8 a = gfrag(wpl + ((mbase + m) * 16 + i16) * 64 + ks * 32 + g8);
                    acc[m][0] = mfma16(a, bf0, acc[m][0]);
                    acc[m][1] = mfma16(a, bf1, acc[m][1]);
                    acc[m][2] = mfma16(a, bf2, acc[m][2]);
                    acc[m][3] = mfma16(a, bf3, acc[m][3]);
                }
            }
        }
    __syncthreads();   // all XT reads done before aliasing as Y2

    #pragma unroll
    for (int m = 0; m < 2; ++m) {
        int ob0 = (mbase + m) * 16 + g4;
        float b0 = beta1[ob0 + 0];
        float b1 = beta1[ob0 + 1];
        float b2 = beta1[ob0 + 2];
        float b3 = beta1[ob0 + 3];
        #pragma unroll
        for (int nt = 0; nt < 4; ++nt) {
            int p = orow * 128 + wbase + nt * 16 + i16;
            u16x4 pk;
            pk[0] = f2b(fmaxf(acc[m][nt][0] + b0, 0.f));
            pk[1] = f2b(fmaxf(acc[m][nt][1] + b1, 0.f));
            pk[2] = f2b(fmaxf(acc[m][nt][2] + b2, 0.f));
            pk[3] = f2b(fmaxf(acc[m][nt][3] + b3, 0.f));
            *(u16x4*)&Y2[p * PITCH + ob0] = pk;
        }
    }
    __syncthreads();

    f32x4 acc2[2][4];
    #pragma unroll
    for (int m = 0; m < 2; ++m)
        #pragma unroll
        for (int nt = 0; nt < 4; ++nt) acc2[m][nt] = zz;

    #pragma unroll
    for (int ks = 0; ks < 2; ++ks) {
        bf16x8 bf0 = frag_load(Y2 + (orow * 128 + wbase + i16) * PITCH + ks * 32 + g8);
        bf16x8 bf1 = frag_load(Y2 + (orow * 128 + wbase + 16 + i16) * PITCH + ks * 32 + g8);
        bf16x8 bf2 = frag_load(Y2 + (orow * 128 + wbase + 32 + i16) * PITCH + ks * 32 + g8);
        bf16x8 bf3 = frag_load(Y2 + (orow * 128 + wbase + 48 + i16) * PITCH + ks * 32 + g8);
        #pragma unroll
        for (int m = 0; m < 2; ++m) {
            bf16x8 a = gfrag(W2b + ((mbase + m) * 16 + i16) * 64 + ks * 32 + g8);
            acc2[m][0] = mfma16(a, bf0, acc2[m][0]);
            acc2[m][1] = mfma16(a, bf1, acc2[m][1]);
            acc2[m][2] = mfma16(a, bf2, acc2[m][2]);
            acc2[m][3] = mfma16(a, bf3, acc2[m][3]);
        }
    }

    float* ob = out + b * CHW + (h0 + orow) * 128 + wbase;
    #pragma unroll
    for (int m = 0; m < 2; ++m)
        #pragma unroll
        for (int r = 0; r < 4; ++r) {
            int o = (mbase + m) * 16 + g4 + r;
            float bt = beta2[o];
            #pragma unroll
            for (int nt = 0; nt < 4; ++nt)
                ob[o * HW + nt * 16 + i16] = fmaxf(acc2[m][nt][r] + bt, 0.f);
        }
}

// ---------------------------------------------------------------------------
extern "C" void kernel_launch(void* const* d_in, const int* in_sizes, int n_in,
                              void* d_out, int out_size, void* d_ws, size_t ws_size,
                              hipStream_t stream)
{
    const float* x1   = (const float*)d_in[0];
    const float* xc   = (const float*)d_in[1];
    const float* Wq   = (const float*)d_in[2];
    const float* bq   = (const float*)d_in[3];
    const float* Wk   = (const float*)d_in[4];
    const float* bk   = (const float*)d_in[5];
    const float* Wv   = (const float*)d_in[6];
    const float* bv   = (const float*)d_in[7];
    const float* gam  = (const float*)d_in[8];
    const float* c1w  = (const float*)d_in[9];
    const float* bn1s = (const float*)d_in[10];
    const float* bn1b = (const float*)d_in[11];
    const float* bn1m = (const float*)d_in[12];
    const float* bn1v = (const float*)d_in[13];
    const float* c2w  = (const float*)d_in[14];
    const float* bn2s = (const float*)d_in[15];
    const float* bn2b = (const float*)d_in[16];
    const float* bn2m = (const float*)d_in[17];
    const float* bn2v = (const float*)d_in[18];
    float* out = (float*)d_out;

    char* ws = (char*)d_ws;
    const size_t BUF = 16777216;   // one bf16 [B,C,H,W] buffer
    unsigned short* qb  = (unsigned short*)(ws);
    unsigned short* kb  = (unsigned short*)(ws + BUF);
    unsigned short* vb  = (unsigned short*)(ws + 2 * BUF);
    unsigned short* yb  = (unsigned short*)(ws + 3 * BUF);
    unsigned short* Wqb = (unsigned short*)(ws + 4 * BUF);
    unsigned short* Wkb = Wqb + 4096;
    unsigned short* Wvb = Wkb + 4096;
    unsigned short* W3b = Wvb + 4096;      // 36864 shorts
    unsigned short* W2b = W3b + 36864;     // 4096 shorts
    float* beta1 = (float*)(W2b + 4096);
    float* beta2 = beta1 + 64;

    prep_kernel<<<209, 256, 0, stream>>>(Wq, Wk, Wv, c1w, bn1s, bn1b, bn1m, bn1v,
                                         c2w, bn2s, bn2b, bn2m, bn2v,
                                         Wqb, Wkb, Wvb, W3b, W2b, beta1, beta2);
    qkv_kernel<<<1024, 256, 0, stream>>>(x1, xc, Wqb, Wkb, Wvb, bq, bk, bv,
                                         qb, kb, vb);
    hipFuncSetAttribute((const void*)attn_kernel,
                        hipFuncAttributeMaxDynamicSharedMemorySize, 67584);
    attn_kernel<<<512, 512, 67584, stream>>>(qb, kb, vb, xc, gam, yb);
    hipFuncSetAttribute((const void*)conv3_fused_kernel,
                        hipFuncAttributeMaxDynamicSharedMemorySize, 70720);
    conv3_fused_kernel<<<512, 512, 70720, stream>>>(yb, W3b, W2b, beta1, beta2, out);
}

// Round 7
// 211.824 us; speedup vs baseline: 3.2164x; 1.0252x over previous
//
#include <hip/hip_runtime.h>

#define HW    16384
#define CHW   1048576
#define EPSV  1e-5f
#define PITCH 68          // rows with K=64 contraction (+4 pad)
#define APITCH 132        // attention rows, K=128 contraction (+4 pad)

typedef short bf16x8 __attribute__((ext_vector_type(8)));
typedef float f32x4 __attribute__((ext_vector_type(4)));
typedef unsigned short u16x4 __attribute__((ext_vector_type(4)));
typedef unsigned short u16x8 __attribute__((ext_vector_type(8)));

static __device__ __forceinline__ unsigned short f2b(float f) {
    union { float f; unsigned int i; } x; x.f = f;
    unsigned int i = x.i + 0x7fffu + ((x.i >> 16) & 1u);   // RNE
    return (unsigned short)(i >> 16);
}

// 8 consecutive bf16 (8B-aligned LDS) as an MFMA operand fragment
static __device__ __forceinline__ bf16x8 frag_load(const unsigned short* p) {
    union { u16x4 h[2]; bf16x8 v; } u;
    u.h[0] = *(const u16x4*)(p);
    u.h[1] = *(const u16x4*)(p + 4);
    return u.v;
}
static __device__ __forceinline__ bf16x8 gfrag(const unsigned short* p) {
    return *(const bf16x8*)p;   // 16B-aligned global load (dwordx4)
}
// D[a_idx = g4+r][b_idx = i16]; both frags loaded with per-lane row = tile+i16
static __device__ __forceinline__ f32x4 mfma16(bf16x8 a, bf16x8 b, f32x4 c) {
    return __builtin_amdgcn_mfma_f32_16x16x32_bf16(a, b, c, 0, 0, 0);
}

// ---------------------------------------------------------------------------
// Kernel 0: weight prep (bf16 conversion + BN folding)
// ---------------------------------------------------------------------------
__global__ void prep_kernel(const float* __restrict__ Wq, const float* __restrict__ Wk,
                            const float* __restrict__ Wv,
                            const float* __restrict__ c1w,
                            const float* __restrict__ bn1s, const float* __restrict__ bn1b,
                            const float* __restrict__ bn1m, const float* __restrict__ bn1v,
                            const float* __restrict__ c2w,
                            const float* __restrict__ bn2s, const float* __restrict__ bn2b,
                            const float* __restrict__ bn2m, const float* __restrict__ bn2v,
                            unsigned short* __restrict__ Wqb, unsigned short* __restrict__ Wkb,
                            unsigned short* __restrict__ Wvb, unsigned short* __restrict__ W3b,
                            unsigned short* __restrict__ W2b, float* __restrict__ beta1,
                            float* __restrict__ beta2)
{
    int i = blockIdx.x * blockDim.x + threadIdx.x;
    if (i < 12288) {                                  // QKV weights: elementwise bf16
        int mat = i >> 12, r = i & 4095;
        const float* src = (mat == 0) ? Wq : ((mat == 1) ? Wk : Wv);
        unsigned short* dst = (mat == 0) ? Wqb : ((mat == 1) ? Wkb : Wvb);
        dst[r] = f2b(src[r]);
    } else if (i < 49152) {                           // conv1 3x3 folded
        int j = i - 12288;
        int dydx = j >> 12, r = j & 4095, o = r >> 6, c = r & 63;
        float inv = bn1s[o] * rsqrtf(bn1v[o] + EPSV);
        W3b[j] = f2b(c1w[o * 576 + c * 9 + dydx] * inv);
    } else if (i < 53248) {                           // conv2 1x1 folded
        int r = i - 49152, o = r >> 6;
        float inv = bn2s[o] * rsqrtf(bn2v[o] + EPSV);
        W2b[r] = f2b(c2w[r] * inv);
    } else if (i < 53376) {
        int j = i - 53248;
        if (j < 64) {
            float inv = bn1s[j] * rsqrtf(bn1v[j] + EPSV);
            beta1[j] = bn1b[j] - bn1m[j] * inv;
        } else {
            int o = j - 64;
            float inv = bn2s[o] * rsqrtf(bn2v[o] + EPSV);
            beta2[o] = bn2b[o] - bn2m[o] * inv;
        }
    }
}

// ---------------------------------------------------------------------------
// Kernel 1: fused Q/K/V 1x1 projections via MFMA.
// A = XT (positions, M=128), B = W (o, N=64) -> lane owns 4 consecutive
// positions at fixed o -> packed u16x4 stores. Weights direct from global.
// LDS: XT [2][128][68] = 34.8 KB -> 4 blocks/CU.
// ---------------------------------------------------------------------------
__global__ __launch_bounds__(256) void qkv_kernel(
    const float* __restrict__ x1, const float* __restrict__ xc,
    const unsigned short* __restrict__ Wqb, const unsigned short* __restrict__ Wkb,
    const unsigned short* __restrict__ Wvb,
    const float* __restrict__ bq, const float* __restrict__ bk,
    const float* __restrict__ bv,
    unsigned short* __restrict__ qo, unsigned short* __restrict__ ko,
    unsigned short* __restrict__ vo)
{
    __shared__ __align__(16) unsigned short XT[2][128][PITCH];
    int t = threadIdx.x;
    int b = blockIdx.x >> 7;
    int p0 = (blockIdx.x & 127) << 7;

    const float* xs1 = x1 + b * CHW + p0;
    const float* xs2 = xc + b * CHW + p0;
    for (int idx = t; idx < 1024; idx += 256) {   // 32 c-pairs x 32 p-quads
        int c0 = ((idx >> 5) & 31) << 1, p4 = (idx & 31) << 2;
        float4 a0 = *(const float4*)&xs1[c0 * HW + p4];
        float4 a1 = *(const float4*)&xs1[(c0 + 1) * HW + p4];
        *(unsigned int*)&XT[0][p4 + 0][c0] = f2b(a0.x) | ((unsigned int)f2b(a1.x) << 16);
        *(unsigned int*)&XT[0][p4 + 1][c0] = f2b(a0.y) | ((unsigned int)f2b(a1.y) << 16);
        *(unsigned int*)&XT[0][p4 + 2][c0] = f2b(a0.z) | ((unsigned int)f2b(a1.z) << 16);
        *(unsigned int*)&XT[0][p4 + 3][c0] = f2b(a0.w) | ((unsigned int)f2b(a1.w) << 16);
        float4 b0 = *(const float4*)&xs2[c0 * HW + p4];
        float4 b1 = *(const float4*)&xs2[(c0 + 1) * HW + p4];
        *(unsigned int*)&XT[1][p4 + 0][c0] = f2b(b0.x) | ((unsigned int)f2b(b1.x) << 16);
        *(unsigned int*)&XT[1][p4 + 1][c0] = f2b(b0.y) | ((unsigned int)f2b(b1.y) << 16);
        *(unsigned int*)&XT[1][p4 + 2][c0] = f2b(b0.z) | ((unsigned int)f2b(b1.z) << 16);
        *(unsigned int*)&XT[1][p4 + 3][c0] = f2b(b0.w) | ((unsigned int)f2b(b1.w) << 16);
    }
    __syncthreads();

    int lane = t & 63, wid = t >> 6;
    int i16 = lane & 15;
    int g8 = (lane >> 4) << 3;
    int g4 = (lane >> 4) << 2;
    int pb = wid << 5;                 // wave's 32 positions (2 m-tiles)

    bf16x8 afr[2][2][2];               // [inp][mi][ks]
    #pragma unroll
    for (int inp = 0; inp < 2; ++inp)
        #pragma unroll
        for (int mi = 0; mi < 2; ++mi)
            #pragma unroll
            for (int ks = 0; ks < 2; ++ks)
                afr[inp][mi][ks] = frag_load(&XT[inp][pb + mi * 16 + i16][ks * 32 + g8]);

    f32x4 zz = {0.f, 0.f, 0.f, 0.f};
    #pragma unroll
    for (int mat = 0; mat < 3; ++mat) {
        const unsigned short* Wmat = (mat == 0) ? Wqb : ((mat == 1) ? Wkb : Wvb);
        unsigned short* dst = ((mat == 0) ? qo : ((mat == 1) ? ko : vo)) + b * CHW + p0;
        const float* bias = (mat == 0) ? bq : ((mat == 1) ? bk : bv);
        const int inp = (mat == 0) ? 0 : 1;

        f32x4 acc[2][4];
        #pragma unroll
        for (int mi = 0; mi < 2; ++mi)
            #pragma unroll
            for (int nt = 0; nt < 4; ++nt) acc[mi][nt] = zz;

        #pragma unroll
        for (int ks = 0; ks < 2; ++ks)
            #pragma unroll
            for (int nt = 0; nt < 4; ++nt) {
                bf16x8 bw = gfrag(Wmat + (nt * 16 + i16) * 64 + ks * 32 + g8);
                acc[0][nt] = mfma16(afr[inp][0][ks], bw, acc[0][nt]);
                acc[1][nt] = mfma16(afr[inp][1][ks], bw, acc[1][nt]);
            }

        #pragma unroll
        for (int nt = 0; nt < 4; ++nt) {
            int o = nt * 16 + i16;
            float bb = bias[o];
            #pragma unroll
            for (int mi = 0; mi < 2; ++mi) {
                u16x4 pk;
                pk[0] = f2b(acc[mi][nt][0] + bb);
                pk[1] = f2b(acc[mi][nt][1] + bb);
                pk[2] = f2b(acc[mi][nt][2] + bb);
                pk[3] = f2b(acc[mi][nt][3] + bb);
                *(u16x4*)&dst[o * HW + pb + mi * 16 + g4] = pk;
            }
        }
    }
}

// ---------------------------------------------------------------------------
// Kernel 2: attention per (b,c), 512 threads / 8 waves, wave owns 16 v-rows.
// QK^T: A=KT, B=QT (softmax reduction stays in-wave). PV swapped: A=PL (v),
// B=V direct-from-global (h) -> y stores packed u16x4, xc reads float4.
// Dynamic LDS: QT,KT [128][132] bf16 = 67584 B -> 2 blocks/CU.
// ---------------------------------------------------------------------------
__global__ __launch_bounds__(512) void attn_kernel(
    const unsigned short* __restrict__ q, const unsigned short* __restrict__ k,
    const unsigned short* __restrict__ v, const float* __restrict__ xc,
    const float* __restrict__ gamma_p, unsigned short* __restrict__ y)
{
    extern __shared__ __align__(16) unsigned short sarena[];
    unsigned short (*QT)[APITCH] = (unsigned short(*)[APITCH])sarena;
    unsigned short (*KT)[APITCH] = (unsigned short(*)[APITCH])(sarena + 16896);
    unsigned short (*PL)[APITCH] = QT;      // aliases QT after phase 1

    int t = threadIdx.x;
    int base = blockIdx.x * HW;

    for (int idx = t; idx < 1024; idx += 512) {    // 64 h-pairs x 16 w-octets
        int h0 = (idx >> 4) << 1, w8 = (idx & 15) << 3;
        u16x8 q0 = *(const u16x8*)&q[base + h0 * 128 + w8];
        u16x8 q1 = *(const u16x8*)&q[base + (h0 + 1) * 128 + w8];
        #pragma unroll
        for (int j = 0; j < 8; ++j)
            *(unsigned int*)&QT[w8 + j][h0] = (unsigned int)q0[j] | ((unsigned int)q1[j] << 16);
        u16x8 k0 = *(const u16x8*)&k[base + h0 * 128 + w8];
        u16x8 k1 = *(const u16x8*)&k[base + (h0 + 1) * 128 + w8];
        #pragma unroll
        for (int j = 0; j < 8; ++j)
            *(unsigned int*)&KT[w8 + j][h0] = (unsigned int)k0[j] | ((unsigned int)k1[j] << 16);
    }
    __syncthreads();

    int lane = t & 63, wid = t >> 6;
    int i16 = lane & 15;
    int g8 = (lane >> 4) << 3;
    int g4 = (lane >> 4) << 2;
    int m0 = wid << 4;               // 16 v-rows per wave

    f32x4 zz = {0.f, 0.f, 0.f, 0.f};
    f32x4 e[8];
    #pragma unroll
    for (int nt = 0; nt < 8; ++nt) e[nt] = zz;

    #pragma unroll
    for (int ks = 0; ks < 4; ++ks) {
        bf16x8 a0 = frag_load(&KT[m0 + i16][ks * 32 + g8]);
        #pragma unroll
        for (int nt = 0; nt < 8; ++nt) {
            bf16x8 bfq = frag_load(&QT[nt * 16 + i16][ks * 32 + g8]);
            e[nt] = mfma16(a0, bfq, e[nt]);
        }
    }
    __syncthreads();   // QT/KT reads complete; QT region becomes PL

    // softmax over w: reduce across nt (regs) and the 16-lane col group
    #pragma unroll
    for (int r = 0; r < 4; ++r) {
        float mx = e[0][r];
        #pragma unroll
        for (int nt = 1; nt < 8; ++nt) mx = fmaxf(mx, e[nt][r]);
        mx = fmaxf(mx, __shfl_xor(mx, 1));
        mx = fmaxf(mx, __shfl_xor(mx, 2));
        mx = fmaxf(mx, __shfl_xor(mx, 4));
        mx = fmaxf(mx, __shfl_xor(mx, 8));
        float pv[8];
        float s = 0.f;
        #pragma unroll
        for (int nt = 0; nt < 8; ++nt) {
            pv[nt] = __expf(e[nt][r] - mx);
            s += pv[nt];
        }
        s += __shfl_xor(s, 1);
        s += __shfl_xor(s, 2);
        s += __shfl_xor(s, 4);
        s += __shfl_xor(s, 8);
        float rinv = 1.f / s;
        int vr = m0 + g4 + r;
        #pragma unroll
        for (int nt = 0; nt < 8; ++nt)
            PL[vr][nt * 16 + i16] = f2b(pv[nt] * rinv);
    }
    // no barrier: PV's A-frags read only this wave's own 16 PL rows

    f32x4 o_[8];
    #pragma unroll
    for (int nt = 0; nt < 8; ++nt) o_[nt] = zz;

    bf16x8 ap[4];
    #pragma unroll
    for (int ks = 0; ks < 4; ++ks)
        ap[ks] = frag_load(&PL[m0 + i16][ks * 32 + g8]);

    const unsigned short* vb_ = v + base;
    #pragma unroll
    for (int ks = 0; ks < 4; ++ks)
        #pragma unroll
        for (int nt = 0; nt < 8; ++nt) {
            bf16x8 bv8 = gfrag(vb_ + (nt * 16 + i16) * 128 + ks * 32 + g8);
            o_[nt] = mfma16(ap[ks], bv8, o_[nt]);
        }

    float g = gamma_p[0];
    const float* xcb = xc + base;
    #pragma unroll
    for (int nt = 0; nt < 8; ++nt) {
        int hh = nt * 16 + i16;
        int v4 = m0 + g4;
        float4 xcv = *(const float4*)&xcb[hh * 128 + v4];
        u16x4 pk;
        pk[0] = f2b(fmaf(g, o_[nt][0], xcv.x));
        pk[1] = f2b(fmaf(g, o_[nt][1], xcv.y));
        pk[2] = f2b(fmaf(g, o_[nt][2], xcv.z));
        pk[3] = f2b(fmaf(g, o_[nt][3], xcv.w));
        *(u16x4*)&y[base + hh * 128 + v4] = pk;
    }
}

// ---------------------------------------------------------------------------
// Kernel 3: 3x3 conv + BN + ReLU + 1x1 conv + BN + ReLU, fused, MFMA.
// conv1: A=W3 (o), B=XT (p) -> packed Y2 u16x4 writes (unchanged).
// conv2 swapped: A=Y2 (p), B=W2 (o2) -> packed float4 output stores.
// Dynamic LDS 70720 B: XT [4][130][68] (Y2 [256][68] aliases) -> 2 blocks/CU.
// ---------------------------------------------------------------------------
__global__ __launch_bounds__(512) void conv3_fused_kernel(
    const unsigned short* __restrict__ yin, const unsigned short* __restrict__ W3b,
    const unsigned short* __restrict__ W2b, const float* __restrict__ beta1,
    const float* __restrict__ beta2, float* __restrict__ out)
{
    extern __shared__ __align__(16) unsigned short arena[];
    unsigned short* XT = arena;              // 4*130*68 = 35360 shorts
    unsigned short* Y2 = arena;              // [256][68] alias (XT dead by then)

    int t = threadIdx.x;
    int b = blockIdx.x >> 6;
    int h0 = (blockIdx.x & 63) << 1;

    u16x4 z4 = {0, 0, 0, 0};
    if (t < 136) {                                    // zero w-halo rows 0,129
        int dy = t / 34, rr = t % 34;
        int row = (rr < 17) ? 0 : 129;
        int q4 = (rr % 17) << 2;
        *(u16x4*)&XT[(dy * 130 + row) * PITCH + q4] = z4;
    }
    const unsigned short* yb = yin + b * CHW;
    for (int idx = t; idx < 2048; idx += 512) {  // 4 dy x 32 c-pairs x 16 w-octets
        int dy = idx >> 9, c0 = ((idx >> 4) & 31) << 1, w8 = (idx & 15) << 3;
        int hh = h0 + dy - 1;
        u16x8 a0 = {0,0,0,0,0,0,0,0}, a1 = {0,0,0,0,0,0,0,0};
        if (hh >= 0 && hh < 128) {
            a0 = *(const u16x8*)&yb[c0 * HW + hh * 128 + w8];
            a1 = *(const u16x8*)&yb[(c0 + 1) * HW + hh * 128 + w8];
        }
        #pragma unroll
        for (int j = 0; j < 8; ++j)
            *(unsigned int*)&XT[(dy * 130 + w8 + 1 + j) * PITCH + c0] =
                (unsigned int)a0[j] | ((unsigned int)a1[j] << 16);
    }
    __syncthreads();

    int lane = t & 63, wid = t >> 6;
    int i16 = lane & 15;
    int g8 = (lane >> 4) << 3;
    int g4 = (lane >> 4) << 2;
    int orow  = wid >> 2;              // output row within pair
    int wbase = ((wid >> 1) & 1) << 6; // 64-wide half of the row
    int mbase = (wid & 1) << 1;        // 2 of the 4 o-tiles

    f32x4 zz = {0.f, 0.f, 0.f, 0.f};
    f32x4 acc[2][4];
    #pragma unroll
    for (int m = 0; m < 2; ++m)
        #pragma unroll
        for (int nt = 0; nt < 4; ++nt) acc[m][nt] = zz;

    #pragma unroll
    for (int dy = 0; dy < 3; ++dy)
        #pragma unroll
        for (int dx = 0; dx < 3; ++dx) {
            const unsigned short* wpl = W3b + (dy * 3 + dx) * 4096;
            const unsigned short* xpl = XT + ((dy + orow) * 130 + dx) * PITCH;
            #pragma unroll
            for (int ks = 0; ks < 2; ++ks) {
                bf16x8 bf0 = frag_load(xpl + (wbase + i16) * PITCH + ks * 32 + g8);
                bf16x8 bf1 = frag_load(xpl + (wbase + 16 + i16) * PITCH + ks * 32 + g8);
                bf16x8 bf2 = frag_load(xpl + (wbase + 32 + i16) * PITCH + ks * 32 + g8);
                bf16x8 bf3 = frag_load(xpl + (wbase + 48 + i16) * PITCH + ks * 32 + g8);
                #pragma unroll
                for (int m = 0; m < 2; ++m) {
                    bf16x8 a = gfrag(wpl + ((mbase + m) * 16 + i16) * 64 + ks * 32 + g8);
                    acc[m][0] = mfma16(a, bf0, acc[m][0]);
                    acc[m][1] = mfma16(a, bf1, acc[m][1]);
                    acc[m][2] = mfma16(a, bf2, acc[m][2]);
                    acc[m][3] = mfma16(a, bf3, acc[m][3]);
                }
            }
        }
    __syncthreads();   // all XT reads done before aliasing as Y2

    #pragma unroll
    for (int m = 0; m < 2; ++m) {
        int ob0 = (mbase + m) * 16 + g4;
        float b0 = beta1[ob0 + 0];
        float b1 = beta1[ob0 + 1];
        float b2 = beta1[ob0 + 2];
        float b3 = beta1[ob0 + 3];
        #pragma unroll
        for (int nt = 0; nt < 4; ++nt) {
            int p = orow * 128 + wbase + nt * 16 + i16;
            u16x4 pk;
            pk[0] = f2b(fmaxf(acc[m][nt][0] + b0, 0.f));
            pk[1] = f2b(fmaxf(acc[m][nt][1] + b1, 0.f));
            pk[2] = f2b(fmaxf(acc[m][nt][2] + b2, 0.f));
            pk[3] = f2b(fmaxf(acc[m][nt][3] + b3, 0.f));
            *(u16x4*)&Y2[p * PITCH + ob0] = pk;
        }
    }
    __syncthreads();

    // conv2 swapped: A = Y2 (p rows), B = W2 (o2 rows)
    int m0c = wid << 5;                // wave's 32 positions
    f32x4 acc2[2][4];
    #pragma unroll
    for (int m = 0; m < 2; ++m)
        #pragma unroll
        for (int nt = 0; nt < 4; ++nt) acc2[m][nt] = zz;

    #pragma unroll
    for (int ks = 0; ks < 2; ++ks) {
        bf16x8 ay0 = frag_load(Y2 + (m0c + i16) * PITCH + ks * 32 + g8);
        bf16x8 ay1 = frag_load(Y2 + (m0c + 16 + i16) * PITCH + ks * 32 + g8);
        #pragma unroll
        for (int nt = 0; nt < 4; ++nt) {
            bf16x8 bw = gfrag(W2b + (nt * 16 + i16) * 64 + ks * 32 + g8);
            acc2[0][nt] = mfma16(ay0, bw, acc2[0][nt]);
            acc2[1][nt] = mfma16(ay1, bw, acc2[1][nt]);
        }
    }

    float* ob = out + b * CHW;
    #pragma unroll
    for (int mi = 0; mi < 2; ++mi)
        #pragma unroll
        for (int nt = 0; nt < 4; ++nt) {
            int o2 = nt * 16 + i16;
            float bt = beta2[o2];
            int p = m0c + mi * 16 + g4;
            int orw = p >> 7, wl = p & 127;
            float4 vv;
            vv.x = fmaxf(acc2[mi][nt][0] + bt, 0.f);
            vv.y = fmaxf(acc2[mi][nt][1] + bt, 0.f);
            vv.z = fmaxf(acc2[mi][nt][2] + bt, 0.f);
            vv.w = fmaxf(acc2[mi][nt][3] + bt, 0.f);
            *(float4*)&ob[o2 * HW + (h0 + orw) * 128 + wl] = vv;
        }
}

// ---------------------------------------------------------------------------
extern "C" void kernel_launch(void* const* d_in, const int* in_sizes, int n_in,
                              void* d_out, int out_size, void* d_ws, size_t ws_size,
                              hipStream_t stream)
{
    const float* x1   = (const float*)d_in[0];
    const float* xc   = (const float*)d_in[1];
    const float* Wq   = (const float*)d_in[2];
    const float* bq   = (const float*)d_in[3];
    const float* Wk   = (const float*)d_in[4];
    const float* bk   = (const float*)d_in[5];
    const float* Wv   = (const float*)d_in[6];
    const float* bv   = (const float*)d_in[7];
    const float* gam  = (const float*)d_in[8];
    const float* c1w  = (const float*)d_in[9];
    const float* bn1s = (const float*)d_in[10];
    const float* bn1b = (const float*)d_in[11];
    const float* bn1m = (const float*)d_in[12];
    const float* bn1v = (const float*)d_in[13];
    const float* c2w  = (const float*)d_in[14];
    const float* bn2s = (const float*)d_in[15];
    const float* bn2b = (const float*)d_in[16];
    const float* bn2m = (const float*)d_in[17];
    const float* bn2v = (const float*)d_in[18];
    float* out = (float*)d_out;

    char* ws = (char*)d_ws;
    const size_t BUF = 16777216;   // one bf16 [B,C,H,W] buffer
    unsigned short* qb  = (unsigned short*)(ws);
    unsigned short* kb  = (unsigned short*)(ws + BUF);
    unsigned short* vb  = (unsigned short*)(ws + 2 * BUF);
    unsigned short* yb  = (unsigned short*)(ws + 3 * BUF);
    unsigned short* Wqb = (unsigned short*)(ws + 4 * BUF);
    unsigned short* Wkb = Wqb + 4096;
    unsigned short* Wvb = Wkb + 4096;
    unsigned short* W3b = Wvb + 4096;      // 36864 shorts
    unsigned short* W2b = W3b + 36864;     // 4096 shorts
    float* beta1 = (float*)(W2b + 4096);
    float* beta2 = beta1 + 64;

    prep_kernel<<<209, 256, 0, stream>>>(Wq, Wk, Wv, c1w, bn1s, bn1b, bn1m, bn1v,
                                         c2w, bn2s, bn2b, bn2m, bn2v,
                                         Wqb, Wkb, Wvb, W3b, W2b, beta1, beta2);
    qkv_kernel<<<1024, 256, 0, stream>>>(x1, xc, Wqb, Wkb, Wvb, bq, bk, bv,
                                         qb, kb, vb);
    hipFuncSetAttribute((const void*)attn_kernel,
                        hipFuncAttributeMaxDynamicSharedMemorySize, 67584);
    attn_kernel<<<512, 512, 67584, stream>>>(qb, kb, vb, xc, gam, yb);
    hipFuncSetAttribute((const void*)conv3_fused_kernel,
                        hipFuncAttributeMaxDynamicSharedMemorySize, 70720);
    conv3_fused_kernel<<<512, 512, 70720, stream>>>(yb, W3b, W2b, beta1, beta2, out);
}